// Round 1
// baseline (4669.082 us; speedup 1.0000x reference)
//
#include <hip/hip_runtime.h>
#include <math.h>

// Problem constants (CustomRNN_1511828488500)
#define Bb 128   // batch
#define Tt 256   // seq len
#define Dd 256   // input dim
#define Hh 256   // hidden dim
#define BH (Bb * Hh)       // 32768
#define WMAT (Hh * Hh)     // 65536
// L = 2 layers, bidirectional; backward direction only needs ONE step:
// out_b[:, -1] is the backward scan's step-0 output = one RNN step on x[:,T-1]
// from h0=0 (Whh_b never read).
//
// Structure (no device-scope sync anywhere):
//   k_gemm (parallel over t): Z0[t] = x[:,t] @ Wih_f[0,t] + b_f[0,t]
//   k_chain (batch-split, 32 WGs, zero inter-WG comm): h0 chain, writes h0_all
//   k_gemm (parallel over t): P[t] = h0_all[t] @ Wih_f[1,t] + b_f[1,t]  (into Z0)
//   k_chain: h1 chain, writes only h1(T-1)
//   k_gemm x2: backward single step, 2 layers;  k_fc: final linear

// ---------------------------------------------------------------------------
// Generic 64x64-tile fp32 GEMM: C[t] = A[t](128x256) @ W[t](256x256) (+bias)(tanh)
// ---------------------------------------------------------------------------
__global__ __launch_bounds__(256) void k_gemm(
    const float* __restrict__ A0, long long Ats, int lda,
    const float* __restrict__ W0, const float* __restrict__ b0,
    float* __restrict__ C0, int dotanh)
{
    __shared__ float Ast[32 * 68];   // A-tile transposed [k][m], pad 68 (16B-aligned rows)
    __shared__ float Bs[32 * 64];    // B-tile [k][n]

    const int t  = blockIdx.y;
    const int m0 = (blockIdx.x >> 2) * 64;
    const int n0 = (blockIdx.x & 3) * 64;
    const float* A = A0 + (size_t)t * (size_t)Ats;
    const float* W = W0 + (size_t)t * WMAT;
    const float* bias = b0 ? b0 + (size_t)t * Hh : (const float*)0;
    float* C = C0 + (size_t)t * BH;

    const int tid = threadIdx.x;
    const int tx = tid & 15, ty = tid >> 4;

    float acc[4][4];
#pragma unroll
    for (int r = 0; r < 4; r++)
#pragma unroll
        for (int c = 0; c < 4; c++) acc[r][c] = 0.f;

    for (int k0 = 0; k0 < 256; k0 += 32) {
#pragma unroll
        for (int i = 0; i < 2; i++) {
            const int idx = tid * 2 + i;
            const int m = idx >> 3, kq = idx & 7;
            const float4 v = *(const float4*)&A[(size_t)(m0 + m) * lda + k0 + kq * 4];
            Ast[(kq * 4 + 0) * 68 + m] = v.x;
            Ast[(kq * 4 + 1) * 68 + m] = v.y;
            Ast[(kq * 4 + 2) * 68 + m] = v.z;
            Ast[(kq * 4 + 3) * 68 + m] = v.w;
        }
#pragma unroll
        for (int i = 0; i < 2; i++) {
            const int idx = tid * 2 + i;
            const int k = idx >> 4, nq = idx & 15;
            *(float4*)&Bs[k * 64 + nq * 4] =
                *(const float4*)&W[(size_t)(k0 + k) * Hh + n0 + nq * 4];
        }
        __syncthreads();
#pragma unroll
        for (int kk = 0; kk < 32; kk++) {
            float a[4], b[4];
            *(float4*)&a[0] = *(const float4*)&Ast[kk * 68 + ty * 4];
            *(float4*)&b[0] = *(const float4*)&Bs[kk * 64 + tx * 4];
#pragma unroll
            for (int r = 0; r < 4; r++)
#pragma unroll
                for (int c = 0; c < 4; c++)
                    acc[r][c] = fmaf(a[r], b[c], acc[r][c]);
        }
        __syncthreads();
    }

    float4 bv = make_float4(0.f, 0.f, 0.f, 0.f);
    if (bias) bv = *(const float4*)&bias[n0 + tx * 4];
#pragma unroll
    for (int r = 0; r < 4; r++) {
        const int m = m0 + ty * 4 + r;
        float4 v = make_float4(acc[r][0] + bv.x, acc[r][1] + bv.y,
                               acc[r][2] + bv.z, acc[r][3] + bv.w);
        if (dotanh) { v.x = tanhf(v.x); v.y = tanhf(v.y); v.z = tanhf(v.z); v.w = tanhf(v.w); }
        *(float4*)&C[(size_t)m * Hh + n0 + tx * 4] = v;
    }
}

// ---------------------------------------------------------------------------
// Batch-split recurrence chain: 32 WGs x 4 batch rows, no inter-WG sync.
// Per step t: h = tanh(Z[t] + h @ W[t]).  W streamed global->LDS via
// global_load_lds dwordx4, double-buffered 64-row chunks (4 chunks/step).
// LDS: sW[2][64][256] (128 KB) | sHt[256][4] (h transposed, 4 KB).
// 8-way k-split partial reduction buffer aliases the idle half of sW.
// ---------------------------------------------------------------------------
#define KC 64
#define NCH (Tt * (Hh / KC))   // 1024 chunks

__device__ __forceinline__ void gload_row16(const float* grow, float* lrow, int lane) {
    // lane l carries floats 4l..4l+3 of a 256-float row; LDS dest = uniform base + lane*16
    __builtin_amdgcn_global_load_lds(
        (const __attribute__((address_space(1))) unsigned int*)(grow + 4 * lane),
        (__attribute__((address_space(3))) unsigned int*)lrow, 16, 0, 0);
}

__global__ __launch_bounds__(256, 1) void k_chain(
    const float* __restrict__ Wc,   // [Tt][256][256] contiguous weight stream
    const float* __restrict__ Zc,   // [Tt][128][256] additive input (incl. bias)
    float* __restrict__ out_all,    // [Tt][128][256] or null
    float* __restrict__ out_last)   // [128][256] or null (written at t = Tt-1)
{
    extern __shared__ float smem[];
    float* sW  = smem;                 // 2 * 16384 floats
    float* red = smem + KC * 256;      // aliases buffer 1 (only used between compute
                                       //   of chunk 4t+3 (buf1) and prefetch into buf1)
    float* sHt = smem + 2 * KC * 256;  // [256][4]: sHt[k][r] = h[r][k]

    const int tid  = threadIdx.x;
    const int lane = tid & 63;
    const int wave = tid >> 6;
    const int cg   = tid & 31;   // col group: cols {4cg..4cg+3} U {128+4cg..+3}
    const int kg   = tid >> 5;   // k group 0..7 (32 k each, spread over 4 chunks)
    const int r0   = blockIdx.x * 4;   // this WG's 4 batch rows

    *(float4*)&sHt[tid * 4] = make_float4(0.f, 0.f, 0.f, 0.f);  // h(-1) = 0

    float acc[4][8];
#pragma unroll
    for (int r = 0; r < 4; r++)
#pragma unroll
        for (int c = 0; c < 8; c++) acc[r][c] = 0.f;

    // prologue: stage chunk 0 (wave w loads rows 16w..16w+15)
#pragma unroll
    for (int rr = 0; rr < 16; rr++) {
        const int row = wave * 16 + rr;
        gload_row16(Wc + (size_t)row * 256, &sW[row * 256], lane);
    }
    __syncthreads();   // compiler drains vmcnt before barrier -> chunk 0 resident

    float zv[4] = {0.f, 0.f, 0.f, 0.f};

    for (int g = 0; g < NCH; ++g) {
        const int bi = g & 1;
        const int t  = g >> 2;
        const int ic = g & 3;
        const float* wbuf = sW + bi * (KC * 256);

        // prefetch chunk g+1 into the other buffer (in flight across this compute)
        if (g + 1 < NCH) {
            const float* gn = Wc + (size_t)(g + 1) * (KC * 256);
            float* lb = sW + (bi ^ 1) * (KC * 256);
#pragma unroll
            for (int rr = 0; rr < 16; rr++) {
                const int row = wave * 16 + rr;
                gload_row16(gn + (size_t)row * 256, lb + row * 256, lane);
            }
        }
        // prefetch Z for this step's epilogue
        if (ic == 3) {
#pragma unroll
            for (int r = 0; r < 4; r++)
                zv[r] = Zc[(size_t)t * BH + (size_t)(r0 + r) * Hh + tid];
        }

        // compute this chunk: thread does rows 0..3 x 8 cols x 8 k
#pragma unroll
        for (int j = 0; j < 8; j++) {
            const int kl = kg * 8 + j;       // k within chunk
            const int ks = ic * KC + kl;     // k within step (0..255)
            float w[8], hv[4];
            *(float4*)&w[0] = *(const float4*)&wbuf[kl * 256 + cg * 4];
            *(float4*)&w[4] = *(const float4*)&wbuf[kl * 256 + 128 + cg * 4];
            *(float4*)&hv[0] = *(const float4*)&sHt[ks * 4];
#pragma unroll
            for (int r = 0; r < 4; r++)
#pragma unroll
                for (int c = 0; c < 8; c++)
                    acc[r][c] = fmaf(hv[r], w[c], acc[r][c]);
        }

        if (ic == 3) {  // step boundary: 8-way k reduction + epilogue
            __syncthreads();   // all waves done reading wbuf(=buf1) and sHt
#pragma unroll
            for (int r = 0; r < 4; r++)
#pragma unroll
                for (int c = 0; c < 8; c++) {
                    red[tid * 33 + r * 8 + c] = acc[r][c];
                    acc[r][c] = 0.f;
                }
            __syncthreads();
            const int n   = tid;                          // output col
            const int rcg = (n & 127) >> 2;               // producing col-group
            const int rc  = (n & 3) + ((n >> 7) << 2);    // producing c index
            float vout[4];
#pragma unroll
            for (int r = 0; r < 4; r++) {
                float s = zv[r];
#pragma unroll
                for (int kk = 0; kk < 8; kk++)
                    s += red[(kk * 32 + rcg) * 33 + r * 8 + rc];
                vout[r] = tanhf(s);
            }
            *(float4*)&sHt[n * 4] = make_float4(vout[0], vout[1], vout[2], vout[3]);
            if (out_all) {
#pragma unroll
                for (int r = 0; r < 4; r++)
                    out_all[(size_t)t * BH + (size_t)(r0 + r) * Hh + n] = vout[r];
            }
            if (out_last && t == Tt - 1) {
#pragma unroll
                for (int r = 0; r < 4; r++)
                    out_last[(size_t)(r0 + r) * Hh + n] = vout[r];
            }
        }
        __syncthreads();   // publishes chunk g+1 (each wave drains own vmcnt) + sHt
    }
}

// out[b][h] = h1fin[b]·fc_w[h][0:256] + hb1[b]·fc_w[h][256:512] + fc_b[h]
__global__ void k_fc(const float* __restrict__ h1fin, const float* __restrict__ hb1,
                     const float* __restrict__ fcw, const float* __restrict__ fcb,
                     float* __restrict__ out) {
    const int b = blockIdx.x;
    const int h = threadIdx.x;  // 256
    __shared__ float last[2 * Hh];
    last[h] = h1fin[(size_t)b * Hh + h];
    last[Hh + h] = hb1[(size_t)b * Hh + h];
    __syncthreads();
    float acc = fcb[h];
    const float* wrow = fcw + (size_t)h * (2 * Hh);
#pragma unroll 4
    for (int j = 0; j < 2 * Hh; j++) acc += last[j] * wrow[j];
    out[(size_t)b * Hh + h] = acc;
}

extern "C" void kernel_launch(void* const* d_in, const int* in_sizes, int n_in,
                              void* d_out, int out_size, void* d_ws, size_t ws_size,
                              hipStream_t stream) {
    const float* x     = (const float*)d_in[0];
    const float* Wih_f = (const float*)d_in[1];
    const float* Whh_f = (const float*)d_in[2];
    const float* b_f   = (const float*)d_in[3];
    const float* Wih_b = (const float*)d_in[4];
    // d_in[5] = Whh_b: provably unused
    const float* b_b   = (const float*)d_in[6];
    const float* fc_w  = (const float*)d_in[7];
    const float* fc_b  = (const float*)d_in[8];
    float* out = (float*)d_out;

    // ws (floats): Z0/P [T*B*H] | h0_all [T*B*H] | hb0 | hb1 | h1l   (~67.6 MB)
    float* ws     = (float*)d_ws;
    float* Z0     = ws;
    float* h0_all = Z0 + (size_t)Tt * BH;
    float* hb0    = h0_all + (size_t)Tt * BH;
    float* hb1    = hb0 + (size_t)BH;
    float* h1l    = hb1 + (size_t)BH;

    const size_t chain_lds = (size_t)(2 * KC * 256 + 1024) * sizeof(float);  // 132 KB
    dim3 blk(256);

    // Z0[t] = x[:,t,:] @ Wih_f[0,t] + b_f[0,t]
    hipLaunchKernelGGL(k_gemm, dim3(8, Tt), blk, 0, stream,
                       x, (long long)Dd, Tt * Dd, Wih_f, b_f, Z0, 0);
    // backward direction: one step at t = T-1, two layers
    hipLaunchKernelGGL(k_gemm, dim3(8, 1), blk, 0, stream,
                       x + (size_t)(Tt - 1) * Dd, 0LL, Tt * Dd,
                       Wih_b + (size_t)(Tt - 1) * WMAT, b_b + (size_t)(Tt - 1) * Hh, hb0, 1);
    hipLaunchKernelGGL(k_gemm, dim3(8, 1), blk, 0, stream,
                       hb0, 0LL, Hh,
                       Wih_b + (size_t)(2 * Tt - 1) * WMAT, b_b + (size_t)(2 * Tt - 1) * Hh, hb1, 1);
    // layer-0 chain (batch-split, no sync): writes h0_all
    hipLaunchKernelGGL(k_chain, dim3(32), blk, chain_lds, stream,
                       Whh_f, Z0, h0_all, (float*)nullptr);
    // P[t] = h0_all[t] @ Wih_f[1,t] + b_f[1,t]   (reuses Z0 buffer)
    hipLaunchKernelGGL(k_gemm, dim3(8, Tt), blk, 0, stream,
                       h0_all, (long long)BH, Hh,
                       Wih_f + (size_t)Tt * WMAT, b_f + (size_t)Tt * Hh, Z0, 0);
    // layer-1 chain: writes only h1(T-1)
    hipLaunchKernelGGL(k_chain, dim3(32), blk, chain_lds, stream,
                       Whh_f + (size_t)Tt * WMAT, Z0, (float*)nullptr, h1l);
    // final linear
    hipLaunchKernelGGL(k_fc, dim3(Bb), blk, 0, stream, h1l, hb1, fc_w, fc_b, out);
}

// Round 2
// 2992.158 us; speedup vs baseline: 1.5604x; 1.5604x over previous
//
#include <hip/hip_runtime.h>
#include <math.h>

// Problem constants (CustomRNN_1511828488500)
#define Bb 128   // batch
#define Tt 256   // seq len
#define Dd 256   // input dim
#define Hh 256   // hidden dim
#define BH (Bb * Hh)       // 32768
#define WMAT (Hh * Hh)     // 65536
// L = 2 layers, bidirectional; backward direction only needs ONE step:
// out_b[:, -1] is the backward scan's step-0 output = one RNN step on x[:,T-1]
// from h0=0 (Whh_b never read).
//
// Structure (no device-scope sync anywhere):
//   k_gemm (parallel over t): Z0[t] = x[:,t] @ Wih_f[0,t] + b_f[0,t]
//   k_chain (batch-split, 32 WGs, zero inter-WG comm): h0 chain, writes h0_all
//   k_gemm (parallel over t): P[t] = h0_all[t] @ Wih_f[1,t] + b_f[1,t]  (into Z0)
//   k_chain: h1 chain, writes only h1(T-1)
//   k_gemm x2: backward single step, 2 layers;  k_fc: final linear
//
// k_chain v2: W streamed straight into REGISTERS (each W element is consumed by
// exactly one thread), double-buffered float4 wa[16]/wb[16]; compiler emits
// counted vmcnt waits -> one full chunk of latency cover, no vmcnt(0) drain.
// LDS holds only sHt (h transposed, 4 KB) + stride-34 reduction buffer (35 KB).
// Barriers: raw s_barrier + lgkmcnt(0) only (W prefetch stays in flight).

// ---------------------------------------------------------------------------
// Generic 64x64-tile fp32 GEMM: C[t] = A[t](128x256) @ W[t](256x256) (+bias)(tanh)
// ---------------------------------------------------------------------------
__global__ __launch_bounds__(256) void k_gemm(
    const float* __restrict__ A0, long long Ats, int lda,
    const float* __restrict__ W0, const float* __restrict__ b0,
    float* __restrict__ C0, int dotanh)
{
    __shared__ float Ast[32 * 68];   // A-tile transposed [k][m], pad 68
    __shared__ float Bs[32 * 64];    // B-tile [k][n]

    const int t  = blockIdx.y;
    const int m0 = (blockIdx.x >> 2) * 64;
    const int n0 = (blockIdx.x & 3) * 64;
    const float* A = A0 + (size_t)t * (size_t)Ats;
    const float* W = W0 + (size_t)t * WMAT;
    const float* bias = b0 ? b0 + (size_t)t * Hh : (const float*)0;
    float* C = C0 + (size_t)t * BH;

    const int tid = threadIdx.x;
    const int tx = tid & 15, ty = tid >> 4;

    float acc[4][4];
#pragma unroll
    for (int r = 0; r < 4; r++)
#pragma unroll
        for (int c = 0; c < 4; c++) acc[r][c] = 0.f;

    for (int k0 = 0; k0 < 256; k0 += 32) {
#pragma unroll
        for (int i = 0; i < 2; i++) {
            const int idx = tid * 2 + i;
            const int m = idx >> 3, kq = idx & 7;
            const float4 v = *(const float4*)&A[(size_t)(m0 + m) * lda + k0 + kq * 4];
            Ast[(kq * 4 + 0) * 68 + m] = v.x;
            Ast[(kq * 4 + 1) * 68 + m] = v.y;
            Ast[(kq * 4 + 2) * 68 + m] = v.z;
            Ast[(kq * 4 + 3) * 68 + m] = v.w;
        }
#pragma unroll
        for (int i = 0; i < 2; i++) {
            const int idx = tid * 2 + i;
            const int k = idx >> 4, nq = idx & 15;
            *(float4*)&Bs[k * 64 + nq * 4] =
                *(const float4*)&W[(size_t)(k0 + k) * Hh + n0 + nq * 4];
        }
        __syncthreads();
#pragma unroll
        for (int kk = 0; kk < 32; kk++) {
            float a[4], b[4];
            *(float4*)&a[0] = *(const float4*)&Ast[kk * 68 + ty * 4];
            *(float4*)&b[0] = *(const float4*)&Bs[kk * 64 + tx * 4];
#pragma unroll
            for (int r = 0; r < 4; r++)
#pragma unroll
                for (int c = 0; c < 4; c++)
                    acc[r][c] = fmaf(a[r], b[c], acc[r][c]);
        }
        __syncthreads();
    }

    float4 bv = make_float4(0.f, 0.f, 0.f, 0.f);
    if (bias) bv = *(const float4*)&bias[n0 + tx * 4];
#pragma unroll
    for (int r = 0; r < 4; r++) {
        const int m = m0 + ty * 4 + r;
        float4 v = make_float4(acc[r][0] + bv.x, acc[r][1] + bv.y,
                               acc[r][2] + bv.z, acc[r][3] + bv.w);
        if (dotanh) { v.x = tanhf(v.x); v.y = tanhf(v.y); v.z = tanhf(v.z); v.w = tanhf(v.w); }
        *(float4*)&C[(size_t)m * Hh + n0 + tx * 4] = v;
    }
}

// ---------------------------------------------------------------------------
// Batch-split recurrence chain: 32 WGs x 4 batch rows, no inter-WG sync.
// ---------------------------------------------------------------------------
#define KC 64
#define NCH (Tt * 4)   // 1024 chunks
#define RSTR 34        // red stride: 2-way (free) bank pattern on write & read

__device__ __forceinline__ void lds_barrier() {
    asm volatile("s_waitcnt lgkmcnt(0)" ::: "memory");
    __builtin_amdgcn_s_barrier();
}

// load chunk g's slice for this thread: rows kg*8..kg*8+7, cols {4cg..+3, 128+4cg..+3}
__device__ __forceinline__ void load_chunk(float4 (&buf)[16], const float* wbase, int g) {
    const float* p = wbase + (size_t)(g < NCH ? g : NCH - 1) * (KC * 256);
#pragma unroll
    for (int j = 0; j < 8; j++) {
        buf[2 * j]     = *(const float4*)(p + (size_t)j * 256);
        buf[2 * j + 1] = *(const float4*)(p + (size_t)j * 256 + 128);
    }
}

__device__ __forceinline__ void comp_chunk(const float4 (&buf)[16], const float* sHt,
                                           int kbase, float (&acc)[4][8]) {
#pragma unroll
    for (int j = 0; j < 8; j++) {
        float hv[4];
        *(float4*)hv = *(const float4*)&sHt[(size_t)(kbase + j) * 4];
        float wv[8];
        *(float4*)&wv[0] = buf[2 * j];
        *(float4*)&wv[4] = buf[2 * j + 1];
#pragma unroll
        for (int r = 0; r < 4; r++)
#pragma unroll
            for (int c = 0; c < 8; c++)
                acc[r][c] = fmaf(hv[r], wv[c], acc[r][c]);
    }
}

__global__ __launch_bounds__(256, 1) void k_chain(
    const float* __restrict__ Wc,   // [Tt][256][256] contiguous weight stream
    const float* __restrict__ Zc,   // [Tt][128][256] additive input (incl. bias)
    float* __restrict__ out_all,    // [Tt][128][256] or null
    float* __restrict__ out_last)   // [128][256] or null (written at t = Tt-1)
{
    __shared__ float sHt[256 * 4];      // sHt[k][r] = h[r][k]
    __shared__ float red[256 * RSTR];   // k-split partial sums

    const int tid = threadIdx.x;
    const int kg  = tid >> 5;    // k group 0..7 (8 k per chunk)
    const int cg  = tid & 31;    // col group: cols {4cg..+3} U {128+4cg..+3}
    const int r0  = blockIdx.x * 4;     // this WG's 4 batch rows

    const float* wbase = Wc + (size_t)(kg * 8) * 256 + cg * 4;

    *(float4*)&sHt[tid * 4] = make_float4(0.f, 0.f, 0.f, 0.f);  // h(-1) = 0
    lds_barrier();

    float acc[4][8];
#pragma unroll
    for (int r = 0; r < 4; r++)
#pragma unroll
        for (int c = 0; c < 8; c++) acc[r][c] = 0.f;

    float4 wa[16], wb[16];
    load_chunk(wa, wbase, 0);
    load_chunk(wb, wbase, 1);

    for (int t = 0; t < Tt; ++t) {
        const int g0 = t * 4;
        float zv[4];
#pragma unroll
        for (int r = 0; r < 4; r++)
            zv[r] = Zc[(size_t)t * BH + (size_t)(r0 + r) * Hh + tid];

        comp_chunk(wa, sHt, 0 * KC + kg * 8, acc);  load_chunk(wa, wbase, g0 + 2);
        comp_chunk(wb, sHt, 1 * KC + kg * 8, acc);  load_chunk(wb, wbase, g0 + 3);
        comp_chunk(wa, sHt, 2 * KC + kg * 8, acc);  load_chunk(wa, wbase, g0 + 4);
        comp_chunk(wb, sHt, 3 * KC + kg * 8, acc);  load_chunk(wb, wbase, g0 + 5);

        // ---- step epilogue: 8-way k reduction + tanh + sHt update ----
#pragma unroll
        for (int r = 0; r < 4; r++)
#pragma unroll
            for (int c = 0; c < 8; c++) {
                red[(size_t)tid * RSTR + r * 8 + c] = acc[r][c];
                acc[r][c] = 0.f;
            }
        lds_barrier();   // red visible; W prefetch stays in flight (no vmcnt drain)

        const int n   = tid;
        const int rcg = (n & 127) >> 2;
        const int rc  = (n & 3) + ((n >> 7) << 2);
        float vout[4];
#pragma unroll
        for (int r = 0; r < 4; r++) {
            float s = zv[r];
#pragma unroll
            for (int kk = 0; kk < 8; kk++)
                s += red[(size_t)(kk * 32 + rcg) * RSTR + r * 8 + rc];
            vout[r] = tanhf(s);
        }
        *(float4*)&sHt[n * 4] = make_float4(vout[0], vout[1], vout[2], vout[3]);
        if (out_all) {
#pragma unroll
            for (int r = 0; r < 4; r++)
                out_all[(size_t)t * BH + (size_t)(r0 + r) * Hh + n] = vout[r];
        }
        if (out_last && t == Tt - 1) {
#pragma unroll
            for (int r = 0; r < 4; r++)
                out_last[(size_t)(r0 + r) * Hh + n] = vout[r];
        }
        lds_barrier();   // new sHt visible before next step's reads
    }
}

// out[b][h] = h1fin[b]·fc_w[h][0:256] + hb1[b]·fc_w[h][256:512] + fc_b[h]
__global__ void k_fc(const float* __restrict__ h1fin, const float* __restrict__ hb1,
                     const float* __restrict__ fcw, const float* __restrict__ fcb,
                     float* __restrict__ out) {
    const int b = blockIdx.x;
    const int h = threadIdx.x;  // 256
    __shared__ float last[2 * Hh];
    last[h] = h1fin[(size_t)b * Hh + h];
    last[Hh + h] = hb1[(size_t)b * Hh + h];
    __syncthreads();
    float acc = fcb[h];
    const float* wrow = fcw + (size_t)h * (2 * Hh);
#pragma unroll 4
    for (int j = 0; j < 2 * Hh; j++) acc += last[j] * wrow[j];
    out[(size_t)b * Hh + h] = acc;
}

extern "C" void kernel_launch(void* const* d_in, const int* in_sizes, int n_in,
                              void* d_out, int out_size, void* d_ws, size_t ws_size,
                              hipStream_t stream) {
    const float* x     = (const float*)d_in[0];
    const float* Wih_f = (const float*)d_in[1];
    const float* Whh_f = (const float*)d_in[2];
    const float* b_f   = (const float*)d_in[3];
    const float* Wih_b = (const float*)d_in[4];
    // d_in[5] = Whh_b: provably unused
    const float* b_b   = (const float*)d_in[6];
    const float* fc_w  = (const float*)d_in[7];
    const float* fc_b  = (const float*)d_in[8];
    float* out = (float*)d_out;

    // ws (floats): Z0/P [T*B*H] | h0_all [T*B*H] | hb0 | hb1 | h1l   (~67.6 MB)
    float* ws     = (float*)d_ws;
    float* Z0     = ws;
    float* h0_all = Z0 + (size_t)Tt * BH;
    float* hb0    = h0_all + (size_t)Tt * BH;
    float* hb1    = hb0 + (size_t)BH;
    float* h1l    = hb1 + (size_t)BH;

    dim3 blk(256);

    // Z0[t] = x[:,t,:] @ Wih_f[0,t] + b_f[0,t]
    hipLaunchKernelGGL(k_gemm, dim3(8, Tt), blk, 0, stream,
                       x, (long long)Dd, Tt * Dd, Wih_f, b_f, Z0, 0);
    // backward direction: one step at t = T-1, two layers
    hipLaunchKernelGGL(k_gemm, dim3(8, 1), blk, 0, stream,
                       x + (size_t)(Tt - 1) * Dd, 0LL, Tt * Dd,
                       Wih_b + (size_t)(Tt - 1) * WMAT, b_b + (size_t)(Tt - 1) * Hh, hb0, 1);
    hipLaunchKernelGGL(k_gemm, dim3(8, 1), blk, 0, stream,
                       hb0, 0LL, Hh,
                       Wih_b + (size_t)(2 * Tt - 1) * WMAT, b_b + (size_t)(2 * Tt - 1) * Hh, hb1, 1);
    // layer-0 chain (batch-split, no sync): writes h0_all
    hipLaunchKernelGGL(k_chain, dim3(32), blk, 0, stream,
                       Whh_f, Z0, h0_all, (float*)nullptr);
    // P[t] = h0_all[t] @ Wih_f[1,t] + b_f[1,t]   (reuses Z0 buffer)
    hipLaunchKernelGGL(k_gemm, dim3(8, Tt), blk, 0, stream,
                       h0_all, (long long)BH, Hh,
                       Wih_f + (size_t)Tt * WMAT, b_f + (size_t)Tt * Hh, Z0, 0);
    // layer-1 chain: writes only h1(T-1)
    hipLaunchKernelGGL(k_chain, dim3(32), blk, 0, stream,
                       Whh_f + (size_t)Tt * WMAT, Z0, (float*)nullptr, h1l);
    // final linear
    hipLaunchKernelGGL(k_fc, dim3(Bb), blk, 0, stream, h1l, hb1, fc_w, fc_b, out);
}